// Round 7
// baseline (139.708 us; speedup 1.0000x reference)
//
#include <hip/hip_runtime.h>
#include <hip/hip_bf16.h>

#define D_MODEL 256
#define N_HEADS 8
#define D_HEAD 32
#define N_LEVELS 4
#define N_POINTS 4
#define LEN_IN 21760
#define N_BATCH 8
#define LEN_Q 1000

#define PROJ_BLOCKS 500   // 8000/16
#define VAL_BLOCKS 2720   // 174080/64

typedef __attribute__((ext_vector_type(8))) short short8;
typedef __attribute__((ext_vector_type(4))) float f32x4;
typedef __attribute__((ext_vector_type(4))) unsigned int u32x4;

typedef const __attribute__((address_space(1))) void* gp1;
typedef __attribute__((address_space(3))) void* lp3;

__device__ __forceinline__ unsigned short f2bf(float f) {
    unsigned int u = __float_as_uint(f);
    u += 0x7FFFu + ((u >> 16) & 1u);   // RNE
    return (unsigned short)(u >> 16);
}
__device__ __forceinline__ float bf2f(unsigned short s) {
    return __uint_as_float(((unsigned int)s) << 16);
}

// ---------------------------------------------------------------------------
// prep:
//   WtVp [8][16][64][8] bf16  <- W_val^T packed MFMA-fragment-major
//   WtC  [384][256] bf16      <- [W_off | W_attn]^T row-major
//   WtO  [256][256] bf16      <- W_out^T row-major
//   bcat [384] f32            <- [b_off | b_attn]
// ---------------------------------------------------------------------------
__global__ __launch_bounds__(256) void prep_kernel(
    const float* __restrict__ Wv, const float* __restrict__ Wo,
    const float* __restrict__ Wa, const float* __restrict__ Wu,
    const float* __restrict__ boff, const float* __restrict__ battn,
    unsigned short* __restrict__ WtVp, unsigned short* __restrict__ WtC,
    unsigned short* __restrict__ WtO, float* __restrict__ bcat)
{
    int idx = blockIdx.x * 256 + threadIdx.x;
    if (idx < 65536) {
        int j = idx & 7, lane = (idx >> 3) & 63, nf = (idx >> 9) & 15, ks = idx >> 13;
        int col = nf * 16 + (lane & 15);
        int k = ks * 32 + (lane >> 4) * 8 + j;
        WtVp[idx] = f2bf(Wv[k * 256 + col]);
    } else if (idx < 65536 + 98304) {
        int j = idx - 65536;
        int n = j >> 8, k = j & 255;
        float s = (n < 256) ? Wo[k * 256 + n] : Wa[k * 128 + (n - 256)];
        WtC[j] = f2bf(s);
    } else if (idx < 65536 + 98304 + 65536) {
        int j = idx - (65536 + 98304);
        int n = j >> 8, k = j & 255;
        WtO[j] = f2bf(Wu[k * 256 + n]);
    } else if (idx < 65536 + 98304 + 65536 + 384) {
        int j = idx - (65536 + 98304 + 65536);
        bcat[j] = (j < 256) ? boff[j] : battn[j - 256];
    }
}

// ---------------------------------------------------------------------------
// Fused kernel: blocks [0, PROJ_BLOCKS) run the query projection
// (proj = query @ [W_off|W_attn] + bcat, BM=16), blocks [PROJ_BLOCKS, ..)
// run the value GEMM. The value GEMM is HBM-bound (MFMA/VALU mostly idle),
// so the proj blocks ride in its shadow instead of serializing after it.
// ---------------------------------------------------------------------------
__global__ __launch_bounds__(256) void fused_vp_kernel(
    const float* __restrict__ A,             // input_flatten
    const unsigned short* __restrict__ Bp,   // WtVp [8][16][64][8]
    const float* __restrict__ biasV,         // b_val
    unsigned short* __restrict__ C,          // value bf16
    const float* __restrict__ Q,             // query
    const unsigned short* __restrict__ WtC,  // [384][256]
    const float* __restrict__ bcat,          // [384]
    float* __restrict__ proj)                // [8000][384]
{
    __shared__ float lds[2][2048];           // used by value path only

    const int tid = threadIdx.x;
    const int wave = tid >> 6, lane = tid & 63;
    const int lhi = lane >> 4, llo = lane & 15;

    if (blockIdx.x < PROJ_BLOCKS) {
        // ----- proj path: BM=16, NF=6, A=f32, C=f32 -----
        const int mBase = blockIdx.x * 16;
        const int colBase = wave * 96;

        f32x4 acc[6];
#pragma unroll
        for (int n = 0; n < 6; ++n)
            acc[n] = (f32x4){0.f, 0.f, 0.f, 0.f};

#pragma unroll
        for (int ks = 0; ks < 8; ++ks) {
            const int kk = ks * 32 + lhi * 8;
            const float* ap = Q + (size_t)(mBase + llo) * 256 + kk;
            f32x4 f0 = *reinterpret_cast<const f32x4*>(ap);
            f32x4 f1 = *reinterpret_cast<const f32x4*>(ap + 4);
            short8 a;
            a[0] = (short)f2bf(f0[0]); a[1] = (short)f2bf(f0[1]);
            a[2] = (short)f2bf(f0[2]); a[3] = (short)f2bf(f0[3]);
            a[4] = (short)f2bf(f1[0]); a[5] = (short)f2bf(f1[1]);
            a[6] = (short)f2bf(f1[2]); a[7] = (short)f2bf(f1[3]);
            short8 b[6];
#pragma unroll
            for (int n = 0; n < 6; ++n)
                b[n] = *reinterpret_cast<const short8*>(
                    WtC + (size_t)(colBase + n * 16 + llo) * 256 + kk);
#pragma unroll
            for (int n = 0; n < 6; ++n)
                acc[n] = __builtin_amdgcn_mfma_f32_16x16x32_bf16(
                    a, b[n], acc[n], 0, 0, 0);
        }

        const int row0 = mBase + lhi * 4;
#pragma unroll
        for (int n = 0; n < 6; ++n) {
            const int col = colBase + n * 16 + llo;
            const float bb = bcat[col];
#pragma unroll
            for (int r = 0; r < 4; ++r)
                proj[(size_t)(row0 + r) * 384 + col] = acc[n][r] + bb;
        }
        return;
    }

    // ----- value path: BM=64, BK=32, double-buffered global_load_lds -----
    const int mBase = (blockIdx.x - PROJ_BLOCKS) * 64;

    const int soff = tid * 16;
    const int r0 = soff >> 7, cb0 = soff & 127;
    const size_t g0 = (size_t)r0 * 1024 + (size_t)(cb0 ^ ((r0 & 7) << 4));
    const size_t g1 = g0 + (size_t)32 * 1024;

    const char* Ab = (const char*)(A + (size_t)mBase * 256);
    const int dsto = soff >> 2;

    f32x4 acc[4][4];
#pragma unroll
    for (int mf = 0; mf < 4; ++mf)
#pragma unroll
        for (int n = 0; n < 4; ++n)
            acc[mf][n] = (f32x4){0.f, 0.f, 0.f, 0.f};

    {
        float* dst0 = &lds[0][dsto];
        __builtin_amdgcn_global_load_lds((gp1)(const void*)(Ab + g0),
                                         (lp3)dst0, 16, 0, 0);
        __builtin_amdgcn_global_load_lds((gp1)(const void*)(Ab + g1),
                                         (lp3)(dst0 + 1024), 16, 0, 0);
    }

#pragma unroll
    for (int kt = 0; kt < 8; ++kt) {
        const int cur = kt & 1;

        short8 b[4];
#pragma unroll
        for (int n = 0; n < 4; ++n)
            b[n] = *reinterpret_cast<const short8*>(
                Bp + ((size_t)(kt * 16 + wave * 4 + n) * 64 + lane) * 8);

        if (kt < 7) {
            const size_t off = (size_t)(kt + 1) * 128;
            float* dst0 = &lds[cur ^ 1][dsto];
            __builtin_amdgcn_global_load_lds((gp1)(const void*)(Ab + off + g0),
                                             (lp3)dst0, 16, 0, 0);
            __builtin_amdgcn_global_load_lds((gp1)(const void*)(Ab + off + g1),
                                             (lp3)(dst0 + 1024), 16, 0, 0);
        }

        __builtin_amdgcn_sched_barrier(0);
        if (kt < 7) asm volatile("s_waitcnt vmcnt(2)" ::: "memory");
        else        asm volatile("s_waitcnt vmcnt(0)" ::: "memory");
        __builtin_amdgcn_sched_barrier(0);
        __builtin_amdgcn_s_barrier();
        __builtin_amdgcn_sched_barrier(0);

        short8 af[4];
#pragma unroll
        for (int mf = 0; mf < 4; ++mf) {
            const int row = mf * 16 + llo;
            const int sz = (llo & 7) << 4;
            const char* base = (const char*)&lds[cur][0] + row * 128;
            f32x4 flo = *reinterpret_cast<const f32x4*>(base + ((lhi * 32) ^ sz));
            f32x4 fhi = *reinterpret_cast<const f32x4*>(base + ((lhi * 32 + 16) ^ sz));
            short8 t;
            t[0] = (short)f2bf(flo[0]); t[1] = (short)f2bf(flo[1]);
            t[2] = (short)f2bf(flo[2]); t[3] = (short)f2bf(flo[3]);
            t[4] = (short)f2bf(fhi[0]); t[5] = (short)f2bf(fhi[1]);
            t[6] = (short)f2bf(fhi[2]); t[7] = (short)f2bf(fhi[3]);
            af[mf] = t;
        }

#pragma unroll
        for (int mf = 0; mf < 4; ++mf)
#pragma unroll
            for (int n = 0; n < 4; ++n)
                acc[mf][n] = __builtin_amdgcn_mfma_f32_16x16x32_bf16(
                    af[mf], b[n], acc[mf][n], 0, 0, 0);

        __builtin_amdgcn_sched_barrier(0);
        __builtin_amdgcn_s_barrier();
        __builtin_amdgcn_sched_barrier(0);
    }

#pragma unroll
    for (int mf = 0; mf < 4; ++mf) {
        const int row0 = mBase + mf * 16 + lhi * 4;
#pragma unroll
        for (int n = 0; n < 4; ++n) {
            const int col = wave * 64 + n * 16 + llo;
            const float bb = biasV[col];
#pragma unroll
            for (int r = 0; r < 4; ++r)
                C[(size_t)(row0 + r) * 256 + col] = f2bf(acc[mf][n][r] + bb);
        }
    }
}

// ---------------------------------------------------------------------------
// Generic K=256 MFMA GEMM, BM=16 (used for the output projection)
// ---------------------------------------------------------------------------
template<int NF, bool ABF16, bool OBF16>
__global__ __launch_bounds__(256) void gemm_k256(
    const void* __restrict__ Av, const unsigned short* __restrict__ Wt,
    const float* __restrict__ bias, void* __restrict__ Cv)
{
    const int wave = threadIdx.x >> 6;
    const int lane = threadIdx.x & 63;
    const int lhi = lane >> 4, llo = lane & 15;
    const int mBase = blockIdx.x * 16;
    const int colBase = wave * (NF * 16);
    const int N = NF * 64;

    f32x4 acc[NF];
#pragma unroll
    for (int n = 0; n < NF; ++n)
        acc[n] = (f32x4){0.f, 0.f, 0.f, 0.f};

#pragma unroll
    for (int ks = 0; ks < 8; ++ks) {
        const int kk = ks * 32 + lhi * 8;
        short8 a;
        if (ABF16) {
            a = *reinterpret_cast<const short8*>(
                (const unsigned short*)Av + (size_t)(mBase + llo) * 256 + kk);
        } else {
            const float* ap = (const float*)Av + (size_t)(mBase + llo) * 256 + kk;
            f32x4 f0 = *reinterpret_cast<const f32x4*>(ap);
            f32x4 f1 = *reinterpret_cast<const f32x4*>(ap + 4);
            short8 t;
            t[0] = (short)f2bf(f0[0]); t[1] = (short)f2bf(f0[1]);
            t[2] = (short)f2bf(f0[2]); t[3] = (short)f2bf(f0[3]);
            t[4] = (short)f2bf(f1[0]); t[5] = (short)f2bf(f1[1]);
            t[6] = (short)f2bf(f1[2]); t[7] = (short)f2bf(f1[3]);
            a = t;
        }
        short8 b[NF];
#pragma unroll
        for (int n = 0; n < NF; ++n) {
            const unsigned short* bp =
                Wt + (size_t)(colBase + n * 16 + llo) * 256 + kk;
            b[n] = *reinterpret_cast<const short8*>(bp);
        }
#pragma unroll
        for (int n = 0; n < NF; ++n)
            acc[n] = __builtin_amdgcn_mfma_f32_16x16x32_bf16(
                a, b[n], acc[n], 0, 0, 0);
    }

    const int row0 = mBase + lhi * 4;
#pragma unroll
    for (int n = 0; n < NF; ++n) {
        const int col = colBase + n * 16 + llo;
        const float bb = bias[col];
#pragma unroll
        for (int r = 0; r < 4; ++r) {
            float v = acc[n][r] + bb;
            size_t idx = (size_t)(row0 + r) * N + col;
            if (OBF16) ((unsigned short*)Cv)[idx] = f2bf(v);
            else       ((float*)Cv)[idx] = v;
        }
    }
}

// ---------------------------------------------------------------------------
// Sampling v5: task-per-lane (as v4) with (a) float2 merged proj/refp loads,
// (b) gathers issued BEFORE the softmax shfl chain so the chain hides under
// gather latency.
// ---------------------------------------------------------------------------
__global__ __launch_bounds__(512) void ms_sample_kernel(
    const unsigned short* __restrict__ value,  // [8*21760][256] bf16
    const float* __restrict__ proj,            // [8000][384] f32
    const float* __restrict__ refp,            // [8][1000][4][2] f32
    unsigned short* __restrict__ out_h)        // [8000][256] bf16
{
    const int bid = blockIdx.x;
    const int b = bid & 7;                     // XCD-pinned batch
    const int q = bid >> 3;
    const int bq = b * LEN_Q + q;

    const int h = threadIdx.x >> 6;            // 0..7
    const int lane = threadIdx.x & 63;
    const int task = lane >> 2;                // 0..15 = l*4+p
    const int l = task >> 2;
    const int qd = lane & 3;                   // dim quarter

    const float* prow = proj + (size_t)bq * 384;

    // ---- address math for this lane's sample (chain head) ----
    const int Wl = 128 >> l;
    const int st = (65536 - (65536 >> (l << 1))) / 3;  // level start row

    const float2 dxy = *reinterpret_cast<const float2*>(prow + h * 32 + 2 * task);
    const float2 rxy = *reinterpret_cast<const float2*>(refp + ((size_t)bq * 4 + l) * 2);

    const float Wlf = (float)Wl;
    const float x = rxy.x * Wlf + dxy.x - 0.5f;
    const float y = rxy.y * Wlf + dxy.y - 0.5f;
    const float x0f = floorf(x), y0f = floorf(y);
    const int x0 = (int)x0f, y0 = (int)y0f;
    const float wx1 = x - x0f, wy1 = y - y0f;
    const float wx0 = 1.f - wx1, wy0 = 1.f - wy1;

    const int x0c = min(max(x0, 0), Wl - 1);
    const int x1c = min(max(x0 + 1, 0), Wl - 1);
    const int y0c = min(max(y0, 0), Wl - 1);
    const int y1c = min(max(y0 + 1, 0), Wl - 1);
    const float fx0 = (x0 >= 0 && x0 < Wl) ? 1.f : 0.f;
    const float fx1 = (x0 + 1 >= 0 && x0 + 1 < Wl) ? 1.f : 0.f;
    const float fy0 = (y0 >= 0 && y0 < Wl) ? 1.f : 0.f;
    const float fy1 = (y0 + 1 >= 0 && y0 + 1 < Wl) ? 1.f : 0.f;

    const int rr0 = st + y0c * Wl, rr1 = st + y1c * Wl;
    const int r00 = rr0 + x0c, r01 = rr0 + x1c;
    const int r10 = rr1 + x0c, r11 = rr1 + x1c;

    // ---- issue all 4 gathers now ----
    const char* vb = (const char*)value + (size_t)b * LEN_IN * 512
                   + h * 64 + qd * 16;
    u32x4 v0 = *reinterpret_cast<const u32x4*>(vb + (size_t)r00 * 512);
    u32x4 v1 = *reinterpret_cast<const u32x4*>(vb + (size_t)r01 * 512);
    u32x4 v2 = *reinterpret_cast<const u32x4*>(vb + (size_t)r10 * 512);
    u32x4 v3 = *reinterpret_cast<const u32x4*>(vb + (size_t)r11 * 512);

    // ---- softmax under gather shadow ----
    float lg = prow[256 + h * 16 + (lane & 15)];
    float mx = lg;
    mx = fmaxf(mx, __shfl_xor(mx, 1, 16));
    mx = fmaxf(mx, __shfl_xor(mx, 2, 16));
    mx = fmaxf(mx, __shfl_xor(mx, 4, 16));
    mx = fmaxf(mx, __shfl_xor(mx, 8, 16));
    float e = __expf(lg - mx);
    float den = e;
    den += __shfl_xor(den, 1, 16);
    den += __shfl_xor(den, 2, 16);
    den += __shfl_xor(den, 4, 16);
    den += __shfl_xor(den, 8, 16);
    const float wsm = e / den;
    const float ws = __shfl(wsm, task, 16);    // this lane's task weight

    float wgt[4];
    wgt[0] = ws * wy0 * wx0 * fy0 * fx0;
    wgt[1] = ws * wy0 * wx1 * fy0 * fx1;
    wgt[2] = ws * wy1 * wx0 * fy1 * fx0;
    wgt[3] = ws * wy1 * wx1 * fy1 * fx1;

    // ---- weighted accumulate: 8 dims per lane ----
    float acc[8];
#pragma unroll
    for (int j = 0; j < 8; ++j) acc[j] = 0.f;
#pragma unroll
    for (int n = 0; n < 4; ++n) {
        const u32x4 v = (n == 0) ? v0 : (n == 1) ? v1 : (n == 2) ? v2 : v3;
        const float wn = wgt[n];
#pragma unroll
        for (int j = 0; j < 4; ++j) {
            const unsigned int u = v[j];
            acc[2 * j]     += wn * bf2f((unsigned short)(u & 0xFFFFu));
            acc[2 * j + 1] += wn * bf2f((unsigned short)(u >> 16));
        }
    }

    // ---- reduce over the 16 tasks (stride-4 lane sets) ----
#pragma unroll
    for (int j = 0; j < 8; ++j) {
        acc[j] += __shfl_xor(acc[j], 4, 64);
        acc[j] += __shfl_xor(acc[j], 8, 64);
        acc[j] += __shfl_xor(acc[j], 16, 64);
        acc[j] += __shfl_xor(acc[j], 32, 64);
    }

    if (task == 0) {
        u32x4 o;
#pragma unroll
        for (int j = 0; j < 4; ++j)
            o[j] = (unsigned int)f2bf(acc[2 * j]) |
                   ((unsigned int)f2bf(acc[2 * j + 1]) << 16);
        *reinterpret_cast<u32x4*>(
            out_h + (size_t)bq * 256 + h * 32 + qd * 8) = o;
    }
}

// ---------------------------------------------------------------------------
extern "C" void kernel_launch(void* const* d_in, const int* in_sizes, int n_in,
                              void* d_out, int out_size, void* d_ws, size_t ws_size,
                              hipStream_t stream)
{
    const float* query  = (const float*)d_in[0];
    const float* refp   = (const float*)d_in[1];
    const float* inpf   = (const float*)d_in[2];
    const float* W_off  = (const float*)d_in[5];
    const float* b_off  = (const float*)d_in[6];
    const float* W_attn = (const float*)d_in[7];
    const float* b_attn = (const float*)d_in[8];
    const float* W_val  = (const float*)d_in[9];
    const float* b_val  = (const float*)d_in[10];
    const float* W_out  = (const float*)d_in[11];
    const float* b_out  = (const float*)d_in[12];

    char* ws = (char*)d_ws;
    unsigned short* value = (unsigned short*)(ws);                    // 89,128,960 B
    float*          proj  = (float*)(ws + 89128960);                  // 12,288,000 B
    unsigned short* out_h = (unsigned short*)(ws + 89128960 + 12288000); // 4,096,000 B
    unsigned short* WtVp  = (unsigned short*)(ws + 109608960);        //    131,072 B
    unsigned short* WtC   = (unsigned short*)(ws + 109740032);        //    196,608 B
    unsigned short* WtO   = (unsigned short*)(ws + 109936640);        //    131,072 B
    float*          bcat  = (float*)(ws + 110067712);                 //      1,536 B

    prep_kernel<<<898, 256, 0, stream>>>(W_val, W_off, W_attn, W_out,
                                         b_off, b_attn, WtVp, WtC, WtO, bcat);

    // value GEMM + proj GEMM co-dispatched (proj rides in the HBM shadow)
    fused_vp_kernel<<<PROJ_BLOCKS + VAL_BLOCKS, 256, 0, stream>>>(
        inpf, WtVp, b_val, value, query, WtC, bcat, proj);

    // bilinear sampling + softmax-weighted sum -> out_h bf16 [8000][256]
    ms_sample_kernel<<<N_BATCH * LEN_Q, 512, 0, stream>>>(
        value, proj, refp, out_h);

    // out = out_h @ W_out + b_out -> d_out f32 [8000][256]
    gemm_k256<4, true, false><<<(N_BATCH * LEN_Q) / 16, 256, 0, stream>>>(
        out_h, WtO, b_out, d_out);
}

// Round 8
// 137.153 us; speedup vs baseline: 1.0186x; 1.0186x over previous
//
#include <hip/hip_runtime.h>
#include <hip/hip_bf16.h>

#define D_MODEL 256
#define N_HEADS 8
#define D_HEAD 32
#define N_LEVELS 4
#define N_POINTS 4
#define LEN_IN 21760
#define N_BATCH 8
#define LEN_Q 1000

typedef __attribute__((ext_vector_type(8))) short short8;
typedef __attribute__((ext_vector_type(4))) float f32x4;
typedef __attribute__((ext_vector_type(4))) unsigned int u32x4;

typedef const __attribute__((address_space(1))) void* gp1;
typedef __attribute__((address_space(3))) void* lp3;

__device__ __forceinline__ unsigned short f2bf(float f) {
    unsigned int u = __float_as_uint(f);
    u += 0x7FFFu + ((u >> 16) & 1u);   // RNE
    return (unsigned short)(u >> 16);
}
__device__ __forceinline__ float bf2f(unsigned short s) {
    return __uint_as_float(((unsigned int)s) << 16);
}

// ---------------------------------------------------------------------------
// prep:
//   WtVp [8][16][64][8] bf16  <- W_val^T packed MFMA-fragment-major
//   WtC  [384][256] bf16      <- [W_off | W_attn]^T row-major
//   WtO  [256][256] bf16      <- W_out^T row-major
//   bcat [384] f32            <- [b_off | b_attn]
// ---------------------------------------------------------------------------
__global__ __launch_bounds__(256) void prep_kernel(
    const float* __restrict__ Wv, const float* __restrict__ Wo,
    const float* __restrict__ Wa, const float* __restrict__ Wu,
    const float* __restrict__ boff, const float* __restrict__ battn,
    unsigned short* __restrict__ WtVp, unsigned short* __restrict__ WtC,
    unsigned short* __restrict__ WtO, float* __restrict__ bcat)
{
    int idx = blockIdx.x * 256 + threadIdx.x;
    if (idx < 65536) {
        int j = idx & 7, lane = (idx >> 3) & 63, nf = (idx >> 9) & 15, ks = idx >> 13;
        int col = nf * 16 + (lane & 15);
        int k = ks * 32 + (lane >> 4) * 8 + j;
        WtVp[idx] = f2bf(Wv[k * 256 + col]);
    } else if (idx < 65536 + 98304) {
        int j = idx - 65536;
        int n = j >> 8, k = j & 255;
        float s = (n < 256) ? Wo[k * 256 + n] : Wa[k * 128 + (n - 256)];
        WtC[j] = f2bf(s);
    } else if (idx < 65536 + 98304 + 65536) {
        int j = idx - (65536 + 98304);
        int n = j >> 8, k = j & 255;
        WtO[j] = f2bf(Wu[k * 256 + n]);
    } else if (idx < 65536 + 98304 + 65536 + 384) {
        int j = idx - (65536 + 98304 + 65536);
        bcat[j] = (j < 256) ? boff[j] : battn[j - 256];
    }
}

// ---------------------------------------------------------------------------
// Value GEMM v2: C_bf16[174080][256] = A_f32[174080][256] @ W_val + bias
// BM=64, BK=32, 256 thr = 4 waves. Depth-2 counted pipeline (T3/T4):
// 3 LDS buffers (24KB); B-frags pipelined 1 iter ahead in regs and issued
// BEFORE the stage ops, so FIFO order per iter kt is:
//   [B(kt+1) x4][S(kt+2) x2] wait vmcnt(8) barrier ds_read+cvt MFMA barrier
// FIFO accounting at iter-kt wait (steady state):
//   outstanding (old->new): S(kt) B(kt) S(kt+1) B(kt+1) S(kt+2)  (2+4+2+4+2)
//   vmcnt(8) leaves newest 8 = {S(kt+1),B(kt+1),S(kt+2)} -> drains S(kt),B(kt)
// Tails: kt=6 -> vmcnt(6), kt=7 -> vmcnt(0).
// Buffer reuse: S(kt+2) writes buf[(kt+2)%3] = buf[(kt-1)%3], whose reads
// were closed by iter kt-1's trailing barrier.
// ---------------------------------------------------------------------------
__global__ __launch_bounds__(256) void gemm_value(
    const float* __restrict__ A,
    const unsigned short* __restrict__ Bp,   // [8][16][64][8] bf16
    const float* __restrict__ bias,
    unsigned short* __restrict__ C)
{
    __shared__ float lds[3][2048];           // 3 x 8KB

    const int tid = threadIdx.x;
    const int wave = tid >> 6, lane = tid & 63;
    const int lhi = lane >> 4, llo = lane & 15;
    const int mBase = blockIdx.x * 64;

    // staging geometry (XOR-swizzled source, linear LDS dest)
    const int soff = tid * 16;
    const int r0 = soff >> 7, cb0 = soff & 127;
    const size_t g0 = (size_t)r0 * 1024 + (size_t)(cb0 ^ ((r0 & 7) << 4));
    const size_t g1 = g0 + (size_t)32 * 1024;
    const char* Ab = (const char*)(A + (size_t)mBase * 256);
    const int dsto = soff >> 2;

#define STAGE(t) { \
        float* dst0 = &lds[(t) % 3][dsto]; \
        const size_t off_ = (size_t)(t) * 128; \
        __builtin_amdgcn_global_load_lds((gp1)(const void*)(Ab + off_ + g0), \
                                         (lp3)dst0, 16, 0, 0); \
        __builtin_amdgcn_global_load_lds((gp1)(const void*)(Ab + off_ + g1), \
                                         (lp3)(dst0 + 1024), 16, 0, 0); }

    f32x4 acc[4][4];
#pragma unroll
    for (int mf = 0; mf < 4; ++mf)
#pragma unroll
        for (int n = 0; n < 4; ++n)
            acc[mf][n] = (f32x4){0.f, 0.f, 0.f, 0.f};

    short8 bcur[4], bnxt[4];

    // prologue: B(0) first (oldest), then stages 0,1
#pragma unroll
    for (int n = 0; n < 4; ++n)
        bcur[n] = *reinterpret_cast<const short8*>(
            Bp + ((size_t)(0 * 16 + wave * 4 + n) * 64 + lane) * 8);
    STAGE(0);
    STAGE(1);

#pragma unroll
    for (int kt = 0; kt < 8; ++kt) {
        // issue next B frags (consumed next iter)
        if (kt < 7) {
#pragma unroll
            for (int n = 0; n < 4; ++n)
                bnxt[n] = *reinterpret_cast<const short8*>(
                    Bp + ((size_t)((kt + 1) * 16 + wave * 4 + n) * 64 + lane) * 8);
        }
        // issue stage kt+2
        if (kt < 6) STAGE(kt + 2);

        __builtin_amdgcn_sched_barrier(0);
        if (kt < 6)      asm volatile("s_waitcnt vmcnt(8)" ::: "memory");
        else if (kt == 6) asm volatile("s_waitcnt vmcnt(6)" ::: "memory");
        else              asm volatile("s_waitcnt vmcnt(0)" ::: "memory");
        __builtin_amdgcn_sched_barrier(0);
        __builtin_amdgcn_s_barrier();
        __builtin_amdgcn_sched_barrier(0);

        // A fragments from lds[kt%3] (swizzled), f32 -> bf16 in-register
        short8 af[4];
#pragma unroll
        for (int mf = 0; mf < 4; ++mf) {
            const int row = mf * 16 + llo;
            const int sz = (llo & 7) << 4;
            const char* base = (const char*)&lds[kt % 3][0] + row * 128;
            f32x4 flo = *reinterpret_cast<const f32x4*>(base + ((lhi * 32) ^ sz));
            f32x4 fhi = *reinterpret_cast<const f32x4*>(base + ((lhi * 32 + 16) ^ sz));
            short8 t;
            t[0] = (short)f2bf(flo[0]); t[1] = (short)f2bf(flo[1]);
            t[2] = (short)f2bf(flo[2]); t[3] = (short)f2bf(flo[3]);
            t[4] = (short)f2bf(fhi[0]); t[5] = (short)f2bf(fhi[1]);
            t[6] = (short)f2bf(fhi[2]); t[7] = (short)f2bf(fhi[3]);
            af[mf] = t;
        }

#pragma unroll
        for (int mf = 0; mf < 4; ++mf)
#pragma unroll
            for (int n = 0; n < 4; ++n)
                acc[mf][n] = __builtin_amdgcn_mfma_f32_16x16x32_bf16(
                    af[mf], bcur[n], acc[mf][n], 0, 0, 0);

        if (kt < 7) {
#pragma unroll
            for (int n = 0; n < 4; ++n) bcur[n] = bnxt[n];
        }

        __builtin_amdgcn_sched_barrier(0);
        __builtin_amdgcn_s_barrier();
        __builtin_amdgcn_sched_barrier(0);
    }
#undef STAGE

    // epilogue: D layout col=lane&15, row=4*(lane>>4)+r
#pragma unroll
    for (int mf = 0; mf < 4; ++mf) {
        const int row0 = mBase + mf * 16 + lhi * 4;
#pragma unroll
        for (int n = 0; n < 4; ++n) {
            const int col = wave * 64 + n * 16 + llo;
            const float bb = bias[col];
#pragma unroll
            for (int r = 0; r < 4; ++r)
                C[(size_t)(row0 + r) * 256 + col] = f2bf(acc[mf][n][r] + bb);
        }
    }
}

// ---------------------------------------------------------------------------
// Generic K=256 MFMA GEMM, BM=16: C[M][N] = A[M][256] @ Wt^T + bias
// ---------------------------------------------------------------------------
template<int NF, bool ABF16, bool OBF16>
__global__ __launch_bounds__(256) void gemm_k256(
    const void* __restrict__ Av, const unsigned short* __restrict__ Wt,
    const float* __restrict__ bias, void* __restrict__ Cv)
{
    const int wave = threadIdx.x >> 6;
    const int lane = threadIdx.x & 63;
    const int lhi = lane >> 4, llo = lane & 15;
    const int mBase = blockIdx.x * 16;
    const int colBase = wave * (NF * 16);
    const int N = NF * 64;

    f32x4 acc[NF];
#pragma unroll
    for (int n = 0; n < NF; ++n)
        acc[n] = (f32x4){0.f, 0.f, 0.f, 0.f};

#pragma unroll
    for (int ks = 0; ks < 8; ++ks) {
        const int kk = ks * 32 + lhi * 8;
        short8 a;
        if (ABF16) {
            a = *reinterpret_cast<const short8*>(
                (const unsigned short*)Av + (size_t)(mBase + llo) * 256 + kk);
        } else {
            const float* ap = (const float*)Av + (size_t)(mBase + llo) * 256 + kk;
            f32x4 f0 = *reinterpret_cast<const f32x4*>(ap);
            f32x4 f1 = *reinterpret_cast<const f32x4*>(ap + 4);
            short8 t;
            t[0] = (short)f2bf(f0[0]); t[1] = (short)f2bf(f0[1]);
            t[2] = (short)f2bf(f0[2]); t[3] = (short)f2bf(f0[3]);
            t[4] = (short)f2bf(f1[0]); t[5] = (short)f2bf(f1[1]);
            t[6] = (short)f2bf(f1[2]); t[7] = (short)f2bf(f1[3]);
            a = t;
        }
        short8 b[NF];
#pragma unroll
        for (int n = 0; n < NF; ++n) {
            const unsigned short* bp =
                Wt + (size_t)(colBase + n * 16 + llo) * 256 + kk;
            b[n] = *reinterpret_cast<const short8*>(bp);
        }
#pragma unroll
        for (int n = 0; n < NF; ++n)
            acc[n] = __builtin_amdgcn_mfma_f32_16x16x32_bf16(
                a, b[n], acc[n], 0, 0, 0);
    }

    const int row0 = mBase + lhi * 4;
#pragma unroll
    for (int n = 0; n < NF; ++n) {
        const int col = colBase + n * 16 + llo;
        const float bb = bias[col];
#pragma unroll
        for (int r = 0; r < 4; ++r) {
            float v = acc[n][r] + bb;
            size_t idx = (size_t)(row0 + r) * N + col;
            if (OBF16) ((unsigned short*)Cv)[idx] = f2bf(v);
            else       ((float*)Cv)[idx] = v;
        }
    }
}

// ---------------------------------------------------------------------------
// Sampling v5: task-per-lane; float2 merged proj/refp loads; gathers issued
// before the softmax shfl chain (softmax hides under gather latency).
// ---------------------------------------------------------------------------
__global__ __launch_bounds__(512) void ms_sample_kernel(
    const unsigned short* __restrict__ value,  // [8*21760][256] bf16
    const float* __restrict__ proj,            // [8000][384] f32
    const float* __restrict__ refp,            // [8][1000][4][2] f32
    unsigned short* __restrict__ out_h)        // [8000][256] bf16
{
    const int bid = blockIdx.x;
    const int b = bid & 7;                     // XCD-pinned batch
    const int q = bid >> 3;
    const int bq = b * LEN_Q + q;

    const int h = threadIdx.x >> 6;            // 0..7
    const int lane = threadIdx.x & 63;
    const int task = lane >> 2;                // 0..15 = l*4+p
    const int l = task >> 2;
    const int qd = lane & 3;                   // dim quarter

    const float* prow = proj + (size_t)bq * 384;

    // ---- address math for this lane's sample ----
    const int Wl = 128 >> l;
    const int st = (65536 - (65536 >> (l << 1))) / 3;  // level start row

    const float2 dxy = *reinterpret_cast<const float2*>(prow + h * 32 + 2 * task);
    const float2 rxy = *reinterpret_cast<const float2*>(refp + ((size_t)bq * 4 + l) * 2);

    const float Wlf = (float)Wl;
    const float x = rxy.x * Wlf + dxy.x - 0.5f;
    const float y = rxy.y * Wlf + dxy.y - 0.5f;
    const float x0f = floorf(x), y0f = floorf(y);
    const int x0 = (int)x0f, y0 = (int)y0f;
    const float wx1 = x - x0f, wy1 = y - y0f;
    const float wx0 = 1.f - wx1, wy0 = 1.f - wy1;

    const int x0c = min(max(x0, 0), Wl - 1);
    const int x1c = min(max(x0 + 1, 0), Wl - 1);
    const int y0c = min(max(y0, 0), Wl - 1);
    const int y1c = min(max(y0 + 1, 0), Wl - 1);
    const float fx0 = (x0 >= 0 && x0 < Wl) ? 1.f : 0.f;
    const float fx1 = (x0 + 1 >= 0 && x0 + 1 < Wl) ? 1.f : 0.f;
    const float fy0 = (y0 >= 0 && y0 < Wl) ? 1.f : 0.f;
    const float fy1 = (y0 + 1 >= 0 && y0 + 1 < Wl) ? 1.f : 0.f;

    const int rr0 = st + y0c * Wl, rr1 = st + y1c * Wl;
    const int r00 = rr0 + x0c, r01 = rr0 + x1c;
    const int r10 = rr1 + x0c, r11 = rr1 + x1c;

    // ---- issue all 4 gathers ----
    const char* vb = (const char*)value + (size_t)b * LEN_IN * 512
                   + h * 64 + qd * 16;
    u32x4 v0 = *reinterpret_cast<const u32x4*>(vb + (size_t)r00 * 512);
    u32x4 v1 = *reinterpret_cast<const u32x4*>(vb + (size_t)r01 * 512);
    u32x4 v2 = *reinterpret_cast<const u32x4*>(vb + (size_t)r10 * 512);
    u32x4 v3 = *reinterpret_cast<const u32x4*>(vb + (size_t)r11 * 512);

    // ---- softmax under gather shadow ----
    float lg = prow[256 + h * 16 + (lane & 15)];
    float mx = lg;
    mx = fmaxf(mx, __shfl_xor(mx, 1, 16));
    mx = fmaxf(mx, __shfl_xor(mx, 2, 16));
    mx = fmaxf(mx, __shfl_xor(mx, 4, 16));
    mx = fmaxf(mx, __shfl_xor(mx, 8, 16));
    float e = __expf(lg - mx);
    float den = e;
    den += __shfl_xor(den, 1, 16);
    den += __shfl_xor(den, 2, 16);
    den += __shfl_xor(den, 4, 16);
    den += __shfl_xor(den, 8, 16);
    const float wsm = e / den;
    const float ws = __shfl(wsm, task, 16);    // this lane's task weight

    float wgt[4];
    wgt[0] = ws * wy0 * wx0 * fy0 * fx0;
    wgt[1] = ws * wy0 * wx1 * fy0 * fx1;
    wgt[2] = ws * wy1 * wx0 * fy1 * fx0;
    wgt[3] = ws * wy1 * wx1 * fy1 * fx1;

    // ---- weighted accumulate: 8 dims per lane ----
    float acc[8];
#pragma unroll
    for (int j = 0; j < 8; ++j) acc[j] = 0.f;
#pragma unroll
    for (int n = 0; n < 4; ++n) {
        const u32x4 v = (n == 0) ? v0 : (n == 1) ? v1 : (n == 2) ? v2 : v3;
        const float wn = wgt[n];
#pragma unroll
        for (int j = 0; j < 4; ++j) {
            const unsigned int u = v[j];
            acc[2 * j]     += wn * bf2f((unsigned short)(u & 0xFFFFu));
            acc[2 * j + 1] += wn * bf2f((unsigned short)(u >> 16));
        }
    }

    // ---- reduce over the 16 tasks (stride-4 lane sets) ----
#pragma unroll
    for (int j = 0; j < 8; ++j) {
        acc[j] += __shfl_xor(acc[j], 4, 64);
        acc[j] += __shfl_xor(acc[j], 8, 64);
        acc[j] += __shfl_xor(acc[j], 16, 64);
        acc[j] += __shfl_xor(acc[j], 32, 64);
    }

    if (task == 0) {
        u32x4 o;
#pragma unroll
        for (int j = 0; j < 4; ++j)
            o[j] = (unsigned int)f2bf(acc[2 * j]) |
                   ((unsigned int)f2bf(acc[2 * j + 1]) << 16);
        *reinterpret_cast<u32x4*>(
            out_h + (size_t)bq * 256 + h * 32 + qd * 8) = o;
    }
}

// ---------------------------------------------------------------------------
extern "C" void kernel_launch(void* const* d_in, const int* in_sizes, int n_in,
                              void* d_out, int out_size, void* d_ws, size_t ws_size,
                              hipStream_t stream)
{
    const float* query  = (const float*)d_in[0];
    const float* refp   = (const float*)d_in[1];
    const float* inpf   = (const float*)d_in[2];
    const float* W_off  = (const float*)d_in[5];
    const float* b_off  = (const float*)d_in[6];
    const float* W_attn = (const float*)d_in[7];
    const float* b_attn = (const float*)d_in[8];
    const float* W_val  = (const float*)d_in[9];
    const float* b_val  = (const float*)d_in[10];
    const float* W_out  = (const float*)d_in[11];
    const float* b_out  = (const float*)d_in[12];

    char* ws = (char*)d_ws;
    unsigned short* value = (unsigned short*)(ws);                    // 89,128,960 B
    float*          proj  = (float*)(ws + 89128960);                  // 12,288,000 B
    unsigned short* out_h = (unsigned short*)(ws + 89128960 + 12288000); // 4,096,000 B
    unsigned short* WtVp  = (unsigned short*)(ws + 109608960);        //    131,072 B
    unsigned short* WtC   = (unsigned short*)(ws + 109740032);        //    196,608 B
    unsigned short* WtO   = (unsigned short*)(ws + 109936640);        //    131,072 B
    float*          bcat  = (float*)(ws + 110067712);                 //      1,536 B

    prep_kernel<<<898, 256, 0, stream>>>(W_val, W_off, W_attn, W_out,
                                         b_off, b_attn, WtVp, WtC, WtO, bcat);

    // value = input_flatten @ W_val + b_val   -> bf16 [174080][256]
    gemm_value<<<(N_BATCH * LEN_IN) / 64, 256, 0, stream>>>(
        inpf, WtVp, b_val, value);

    // proj = query @ [W_off|W_attn] + bias -> f32 [8000][384]
    gemm_k256<6, false, false><<<(N_BATCH * LEN_Q) / 16, 256, 0, stream>>>(
        query, WtC, bcat, (void*)proj);

    // bilinear sampling + softmax-weighted sum -> out_h bf16 [8000][256]
    ms_sample_kernel<<<N_BATCH * LEN_Q, 512, 0, stream>>>(
        value, proj, refp, out_h);

    // out = out_h @ W_out + b_out -> d_out f32 [8000][256]
    gemm_k256<4, true, false><<<(N_BATCH * LEN_Q) / 16, 256, 0, stream>>>(
        out_h, WtO, b_out, d_out);
}